// Round 9
// baseline (139.450 us; speedup 1.0000x reference)
//
#include <hip/hip_runtime.h>
#include <hip/hip_bf16.h>

#define BS 4
#define NF 8
#define NT 256
#define DIN 64
#define NH 8
#define DOUT 64
#define TT 4          // t's per attn block (one wave per t)
#define MROWS 32      // TT*NH score rows per block
#define NCH 64        // NT/TT

typedef unsigned short u16;
typedef __attribute__((ext_vector_type(8))) short short8;
typedef __attribute__((ext_vector_type(4))) float f32x4;
typedef __attribute__((ext_vector_type(4))) unsigned int u32x4;

static __device__ __forceinline__ u16 f2bf(float x) {
    __hip_bfloat16 h = __float2bfloat16(x);
    u16 r; __builtin_memcpy(&r, &h, 2); return r;
}
static __device__ __forceinline__ unsigned pk2(float a, float b) {
    return (unsigned)f2bf(a) | ((unsigned)f2bf(b) << 16);
}

// ---------------------------------------------------------------------------
// prep: [0,2048) qk projection, block per (f,t); q stored [bf][t][he],
//   K stored TRANSPOSED kT[bf][he][t].  (UNCHANGED from round 8.)
//   [2048,2176) X -> XT bf16 [bf][d][l] ; [2176,2240) W -> Wt bf16 [f][o][kk]
// ---------------------------------------------------------------------------
__global__ __launch_bounds__(256) void prep_kernel(
    const float* __restrict__ X,
    const float* __restrict__ Wq,
    const float* __restrict__ Wk,
    const float* __restrict__ W,
    float* __restrict__ q,
    float* __restrict__ kT,
    u16* __restrict__ XT,
    u16* __restrict__ Wt)
{
    __shared__ float sm[4160];          // union: qk {sWt[2176], sX[256]} | sT[64][65]
    const int tid = threadIdx.x;
    const int bid = blockIdx.x;

    if (bid < 2048) {
        const int ft = bid;             // f*NT + t
        const int f = ft >> 8, t = ft & 255;
        float* sWt = sm;                // [which*1088 + he*68 + d]
        float* sX  = sm + 2176;         // [b*64 + d]

        float4 a4 = ((const float4*)(Wq + ((size_t)ft << 10)))[tid];
        float4 b4 = ((const float4*)(Wk + ((size_t)ft << 10)))[tid];
        {
            int d = tid >> 2, he = (tid & 3) << 2;
            sWt[(he + 0) * 68 + d] = a4.x;
            sWt[(he + 1) * 68 + d] = a4.y;
            sWt[(he + 2) * 68 + d] = a4.z;
            sWt[(he + 3) * 68 + d] = a4.w;
            sWt[1088 + (he + 0) * 68 + d] = b4.x;
            sWt[1088 + (he + 1) * 68 + d] = b4.y;
            sWt[1088 + (he + 2) * 68 + d] = b4.z;
            sWt[1088 + (he + 3) * 68 + d] = b4.w;
            int xb = tid >> 6, xd = tid & 63;
            sX[tid] = X[(((size_t)((xb * NF + f) * NT + t)) << 6) + xd];
        }
        __syncthreads();

        const int half  = tid & 1;
        const int he    = (tid >> 1) & 15;
        const int b     = (tid >> 5) & 3;
        const int which = tid >> 7;
        const float* wp = sWt + which * 1088 + he * 68 + (half << 5);
        const float* xp = sX + (b << 6) + (half << 5);
        float acc = 0.f;
        #pragma unroll
        for (int j = 0; j < 8; ++j) {
            float4 w = *(const float4*)(wp + (j << 2));
            float4 x = *(const float4*)(xp + (j << 2));
            acc = fmaf(w.x, x.x, acc);
            acc = fmaf(w.y, x.y, acc);
            acc = fmaf(w.z, x.z, acc);
            acc = fmaf(w.w, x.w, acc);
        }
        acc += __shfl_xor(acc, 1);
        if (half == 0) {
            int bf = b * NF + f;
            if (which) kT[(((size_t)(bf * 16 + he)) << 8) + t] = acc;
            else       q[(((size_t)(bf * NT + t)) << 4) + he] = acc;
        }
    } else if (bid < 2176) {
        const int idx = bid - 2048;     // (bf, lc)
        const int bf = idx >> 2, lc = idx & 3;
        float (*sT)[65] = (float(*)[65])sm;
        #pragma unroll
        for (int i = 0; i < 16; ++i) {
            int l = i * 4 + (tid >> 6), d = tid & 63;
            sT[l][d] = X[(((size_t)(bf * NT) + lc * 64 + l) << 6) + d];
        }
        __syncthreads();
        #pragma unroll
        for (int i = 0; i < 16; ++i) {
            int d = i * 4 + (tid >> 6), l = tid & 63;
            XT[(((size_t)(bf * 64) + d) << 8) + lc * 64 + l] = f2bf(sT[l][d]);
        }
    } else {
        const int idx = bid - 2176;
        const int f = idx >> 3, kc = idx & 7;
        float (*sT)[65] = (float(*)[65])sm;
        #pragma unroll
        for (int i = 0; i < 16; ++i) {
            int kk = i * 4 + (tid >> 6), o = tid & 63;
            sT[kk][o] = W[(((size_t)(f * 512) + kc * 64 + kk) << 6) + o];
        }
        __syncthreads();
        #pragma unroll
        for (int i = 0; i < 16; ++i) {
            int o = i * 4 + (tid >> 6), kk = tid & 63;
            Wt[(((size_t)(f * 64) + o) << 9) + kc * 64 + kk] = f2bf(sT[kk][o]);
        }
    }
}

// ---------------------------------------------------------------------------
// attn v9: block = (b, f, 4-t chunk); ONE WAVE PER t. Lane = (lg,h): one
// contiguous 32-l segment of one score row. Softmax reductions are pure
// shfl_xor (8,16,32) -- no LDS, no barrier. Only 3 barriers total:
// sP ready -> MFMA P@X -> sP reads done -> sVals ready -> MFMA vals@W.
// ---------------------------------------------------------------------------
__global__ __launch_bounds__(256, 4) void attn_kernel(
    const float* __restrict__ ac,
    const float* __restrict__ alpha,
    const float* __restrict__ Wkey_,
    const float* __restrict__ u,
    const float* __restrict__ bias,
    const float* __restrict__ q,
    const float* __restrict__ kT,
    const u16* __restrict__ XT,
    const u16* __restrict__ Wt,
    float* __restrict__ out)
{
    __shared__ __align__(16) u16 sPV[8320];  // sP[32][256] | sVals[16][520]
    __shared__ float sInvS[MROWS];

    const int tid = threadIdx.x;
    const int bid = blockIdx.x;
    const int ch = bid & 63;
    const int f  = (bid >> 6) & 7;
    const int b  = bid >> 9;
    const int bf = b * NF + f;
    const int t0 = ch * TT;

    const int w    = tid >> 6;        // wave = t_local
    const int lane = tid & 63;
    const int h    = lane & 7;
    const int lg   = lane >> 3;       // 0..7 -> l segment
    const int t    = t0 + w;
    const int m    = w * 8 + h;       // score row (t_local = m>>3, h = m&7)
    const int l0   = lg * 32;

    const int quad = lane >> 4;
    const int ln   = lane & 15;
    const int mh   = w & 1;           // m-half for phase 3
    const int nh2  = w >> 1;          // n-half for phase 3

    // ---- prefetch phase-3 XT ks=0 b-frags at the very top ----
    const u16* xb = XT + ((size_t)bf << 14);
    short8 nb0 = *(const short8*)(xb + (nh2 * 32 + ln) * 256 + quad * 8);
    short8 nb1 = *(const short8*)(xb + (nh2 * 32 + 16 + ln) * 256 + quad * 8);

    const float* kT0 = kT + ((size_t)bf << 12) + ((h * 2) << 8);  // comp0 row [t]
    const float* kT1 = kT0 + 256;
    const float* up  = u + (f << 9);

    // ---- per-row constants ----
    float q0, q1, kt0, kt1, c2, c1;
    {
        float al = alpha[f];
        float acv = ac[f * 8 + h];
        float wk0 = Wkey_[f * 4],     wk1 = Wkey_[f * 4 + 1];
        float wk2 = Wkey_[f * 4 + 2], wk3 = Wkey_[f * 4 + 3];
        float2 qv = *(const float2*)(q + ((size_t)(bf * NT + t) << 4) + (h << 1));
        q0 = qv.x; q1 = qv.y;
        kt0 = kT0[t]; kt1 = kT1[t];
        float a0 = q0 - al, a1 = q1 + 2.f * al * acv;
        c2 = a0 * wk0 + a1 * wk2; c1 = a0 * wk1 + a1 * wk3;
    }

    // ---- scores: 32 contiguous l's, loads hoisted per 8-l group ----
    float s[32];
    float mx = -1e30f;
    #pragma unroll
    for (int g = 0; g < 4; ++g) {
        const int lb = l0 + g * 8;
        float4 K0a = *(const float4*)(kT0 + lb);
        float4 K0b = *(const float4*)(kT0 + lb + 4);
        float4 K1a = *(const float4*)(kT1 + lb);
        float4 K1b = *(const float4*)(kT1 + lb + 4);
        float4 Ua = *(const float4*)(up + (lb << 1));
        float4 Ub = *(const float4*)(up + (lb << 1) + 4);
        float4 Uc = *(const float4*)(up + (lb << 1) + 8);
        float4 Ud = *(const float4*)(up + (lb << 1) + 12);
        float k0[8] = {K0a.x, K0a.y, K0a.z, K0a.w, K0b.x, K0b.y, K0b.z, K0b.w};
        float k1[8] = {K1a.x, K1a.y, K1a.z, K1a.w, K1b.x, K1b.y, K1b.z, K1b.w};
        float u0[8] = {Ua.x, Ua.z, Ub.x, Ub.z, Uc.x, Uc.z, Ud.x, Ud.z};
        float u1[8] = {Ua.y, Ua.w, Ub.y, Ub.w, Uc.y, Uc.w, Ud.y, Ud.w};
        #pragma unroll
        for (int j = 0; j < 8; ++j) {
            float rel = (float)(lb + j - t);
            float sv = (c2 * rel + c1) * rel;
            sv = fmaf(q0, k0[j], sv);
            sv = fmaf(q1, k1[j], sv);
            sv = fmaf(kt0, u0[j], sv);
            sv = fmaf(kt1, u1[j], sv);
            s[g * 8 + j] = sv;
            mx = fmaxf(mx, sv);
        }
    }
    // ---- row max: pure shfl over the 8 lg-lanes of this row ----
    mx = fmaxf(mx, __shfl_xor(mx, 8));
    mx = fmaxf(mx, __shfl_xor(mx, 16));
    mx = fmaxf(mx, __shfl_xor(mx, 32));

    // ---- exp, pack to sP (bf16, unnormalized), row sum via shfl ----
    u16* sP = sPV;
    float sum = 0.f;
    #pragma unroll
    for (int c = 0; c < 4; ++c) {
        unsigned pk4[4];
        #pragma unroll
        for (int jj = 0; jj < 8; jj += 2) {
            float e0 = __expf(s[c * 8 + jj] - mx);
            float e1 = __expf(s[c * 8 + jj + 1] - mx);
            sum += e0 + e1;
            pk4[jj >> 1] = pk2(e0, e1);
        }
        int chunk = lg * 4 + c;
        int phys = chunk ^ (m & 15);
        *(u32x4*)&sP[m * 256 + phys * 8] = (u32x4){pk4[0], pk4[1], pk4[2], pk4[3]};
    }
    sum += __shfl_xor(sum, 8);
    sum += __shfl_xor(sum, 16);
    sum += __shfl_xor(sum, 32);
    if (lg == 0) sInvS[m] = 1.f / sum;
    __syncthreads();                        // B1: sP + sInvS ready

    // ---- phase 3: vals = P @ X via pipelined MFMA (M=32, K=256, N=64) ----
    f32x4 acc0 = {0.f, 0.f, 0.f, 0.f}, acc1 = acc0;
    #pragma unroll
    for (int ks = 0; ks < 8; ++ks) {
        short8 b0 = nb0, b1 = nb1;
        if (ks < 7) {
            int l2 = (ks + 1) * 32 + quad * 8;
            nb0 = *(const short8*)(xb + (nh2 * 32 + ln) * 256 + l2);
            nb1 = *(const short8*)(xb + (nh2 * 32 + 16 + ln) * 256 + l2);
        }
        int phys = (ks * 4 + quad) ^ ln;
        short8 a = *(const short8*)&sP[(mh * 16 + ln) * 256 + phys * 8];
        acc0 = __builtin_amdgcn_mfma_f32_16x16x32_bf16(a, b0, acc0, 0, 0, 0);
        acc1 = __builtin_amdgcn_mfma_f32_16x16x32_bf16(a, b1, acc1, 0, 0, 0);
    }
    float inv0 = sInvS[mh * 16 + quad * 4 + 0];
    float inv1 = sInvS[mh * 16 + quad * 4 + 1];
    float inv2 = sInvS[mh * 16 + quad * 4 + 2];
    float inv3 = sInvS[mh * 16 + quad * 4 + 3];
    const u16* wb = Wt + ((size_t)(f * 64 + w * 16 + ln) << 9);
    short8 nw = *(const short8*)(wb + quad * 8);   // prefetch phase-4 ks=0
    __syncthreads();                        // B2: all sP reads complete

    // ---- sVals (overlays sP) ----
    u16* sVals = sPV;   // [tl][520]
    {
        float invs[4] = {inv0, inv1, inv2, inv3};
        #pragma unroll
        for (int reg = 0; reg < 4; ++reg) {
            int mg = mh * 16 + quad * 4 + reg;
            int tl = mg >> 3, hh = mg & 7;
            u16* dst = sVals + tl * 520 + hh * 64 + nh2 * 32 + ln;
            dst[0]  = f2bf(acc0[reg] * invs[reg]);
            dst[16] = f2bf(acc1[reg] * invs[reg]);
        }
    }
    __syncthreads();                        // B3: sVals ready

    // ---- phase 4: out = vals @ W via pipelined MFMA (M=4(pad16), K=512) ----
    f32x4 oacc = {0.f, 0.f, 0.f, 0.f};
    #pragma unroll
    for (int ks = 0; ks < 16; ++ks) {
        short8 bw = nw;
        if (ks < 15) nw = *(const short8*)(wb + (ks + 1) * 32 + quad * 8);
        short8 a = *(const short8*)(sVals + ln * 520 + ks * 32 + quad * 8);
        oacc = __builtin_amdgcn_mfma_f32_16x16x32_bf16(a, bw, oacc, 0, 0, 0);
    }
    {
        int o = w * 16 + ln;
        #pragma unroll
        for (int reg = 0; reg < 4; ++reg) {
            int tl = quad * 4 + reg;
            if (tl < TT) {
                int tg = t0 + tl;
                out[((size_t)(bf * NT + tg) << 6) + o] =
                    oacc[reg] + bias[((size_t)(f * NT + tg) << 6) + o];
            }
        }
    }
}

extern "C" void kernel_launch(void* const* d_in, const int* in_sizes, int n_in,
                              void* d_out, int out_size, void* d_ws, size_t ws_size,
                              hipStream_t stream) {
    const float* X     = (const float*)d_in[0];
    const float* ac    = (const float*)d_in[1];
    const float* alpha = (const float*)d_in[2];
    const float* Wq    = (const float*)d_in[3];
    const float* Wk    = (const float*)d_in[4];
    const float* Wkey_ = (const float*)d_in[5];
    const float* u     = (const float*)d_in[6];
    const float* W     = (const float*)d_in[7];
    const float* bb    = (const float*)d_in[8];
    float* out = (float*)d_out;

    float* qws = (float*)d_ws;                  // 131072 f
    float* kTp = qws + 131072;                  // 131072 f (transposed K)
    u16* XT = (u16*)(kTp + 131072);             // 524288 u16
    u16* Wt = XT + 524288;                      // 262144 u16

    hipLaunchKernelGGL(prep_kernel, dim3(2240), dim3(256), 0, stream,
                       X, Wq, Wk, W, qws, kTp, XT, Wt);
    hipLaunchKernelGGL(attn_kernel, dim3(BS * NF * NCH), dim3(256), 0, stream,
                       ac, alpha, Wkey_, u, bb, qws, kTp, XT, Wt, out);
}

// Round 10
// 116.657 us; speedup vs baseline: 1.1954x; 1.1954x over previous
//
#include <hip/hip_runtime.h>
#include <hip/hip_bf16.h>

#define BS 4
#define NF 8
#define NT 256
#define DIN 64
#define NH 8
#define DOUT 64
#define TT 4          // t's per attn block
#define MROWS 32      // TT*NH score rows per block
#define NCH 64        // NT/TT

typedef unsigned short u16;
typedef __attribute__((ext_vector_type(8))) short short8;
typedef __attribute__((ext_vector_type(4))) float f32x4;
typedef __attribute__((ext_vector_type(4))) unsigned int u32x4;

static __device__ __forceinline__ u16 f2bf(float x) {
    __hip_bfloat16 h = __float2bfloat16(x);
    u16 r; __builtin_memcpy(&r, &h, 2); return r;
}
static __device__ __forceinline__ unsigned pk2(float a, float b) {
    return (unsigned)f2bf(a) | ((unsigned)f2bf(b) << 16);
}

// ---------------------------------------------------------------------------
// prep (R7 version, proven): [0,2048) qk projection, block per (f,t);
//   Wq/Wk staged transposed in LDS, b128 compute reads; q/k normal layout.
//   [2048,2176) X -> XT bf16 [bf][d][l] ; [2176,2240) W -> Wt bf16 [f][o][kk]
// ---------------------------------------------------------------------------
__global__ __launch_bounds__(256) void prep_kernel(
    const float* __restrict__ X,
    const float* __restrict__ Wq,
    const float* __restrict__ Wk,
    const float* __restrict__ W,
    float* __restrict__ q,
    float* __restrict__ k,
    u16* __restrict__ XT,
    u16* __restrict__ Wt)
{
    __shared__ float sm[4160];          // union: qk {sWt[2176], sX[256]} | sT[64][65]
    const int tid = threadIdx.x;
    const int bid = blockIdx.x;

    if (bid < 2048) {
        const int ft = bid;             // f*NT + t
        const int f = ft >> 8, t = ft & 255;
        float* sWt = sm;                // [which*1088 + he*68 + d]
        float* sX  = sm + 2176;         // [b*64 + d]

        float4 a4 = ((const float4*)(Wq + ((size_t)ft << 10)))[tid];
        float4 b4 = ((const float4*)(Wk + ((size_t)ft << 10)))[tid];
        {
            int d = tid >> 2, he = (tid & 3) << 2;
            sWt[(he + 0) * 68 + d] = a4.x;
            sWt[(he + 1) * 68 + d] = a4.y;
            sWt[(he + 2) * 68 + d] = a4.z;
            sWt[(he + 3) * 68 + d] = a4.w;
            sWt[1088 + (he + 0) * 68 + d] = b4.x;
            sWt[1088 + (he + 1) * 68 + d] = b4.y;
            sWt[1088 + (he + 2) * 68 + d] = b4.z;
            sWt[1088 + (he + 3) * 68 + d] = b4.w;
            int xb = tid >> 6, xd = tid & 63;
            sX[tid] = X[(((size_t)((xb * NF + f) * NT + t)) << 6) + xd];
        }
        __syncthreads();

        const int half  = tid & 1;
        const int he    = (tid >> 1) & 15;
        const int b     = (tid >> 5) & 3;
        const int which = tid >> 7;
        const float* wp = sWt + which * 1088 + he * 68 + (half << 5);
        const float* xp = sX + (b << 6) + (half << 5);
        float acc = 0.f;
        #pragma unroll
        for (int j = 0; j < 8; ++j) {
            float4 w = *(const float4*)(wp + (j << 2));
            float4 x = *(const float4*)(xp + (j << 2));
            acc = fmaf(w.x, x.x, acc);
            acc = fmaf(w.y, x.y, acc);
            acc = fmaf(w.z, x.z, acc);
            acc = fmaf(w.w, x.w, acc);
        }
        acc += __shfl_xor(acc, 1);
        if (half == 0) {
            float* outp = which ? k : q;
            outp[(((size_t)((b * NF + f) * NT + t)) << 4) + he] = acc;
        }
    } else if (bid < 2176) {
        const int idx = bid - 2048;     // (bf, lc)
        const int bf = idx >> 2, lc = idx & 3;
        float (*sT)[65] = (float(*)[65])sm;
        #pragma unroll
        for (int i = 0; i < 16; ++i) {
            int l = i * 4 + (tid >> 6), d = tid & 63;
            sT[l][d] = X[(((size_t)(bf * NT) + lc * 64 + l) << 6) + d];
        }
        __syncthreads();
        #pragma unroll
        for (int i = 0; i < 16; ++i) {
            int d = i * 4 + (tid >> 6), l = tid & 63;
            XT[(((size_t)(bf * 64) + d) << 8) + lc * 64 + l] = f2bf(sT[l][d]);
        }
    } else {
        const int idx = bid - 2176;
        const int f = idx >> 3, kc = idx & 7;
        float (*sT)[65] = (float(*)[65])sm;
        #pragma unroll
        for (int i = 0; i < 16; ++i) {
            int kk = i * 4 + (tid >> 6), o = tid & 63;
            sT[kk][o] = W[(((size_t)(f * 512) + kc * 64 + kk) << 6) + o];
        }
        __syncthreads();
        #pragma unroll
        for (int i = 0; i < 16; ++i) {
            int o = i * 4 + (tid >> 6), kk = tid & 63;
            Wt[(((size_t)(f * 64) + o) << 9) + kc * 64 + kk] = f2bf(sT[kk][o]);
        }
    }
}

// ---------------------------------------------------------------------------
// attn v10 = R6/R7 structure (best measured) + LDS overlay:
// sKU (18 KB, dead after pass A) | sP (16 KB, born in pass B) | sVals share
// one region -> 20.7 KB total -> 7 blocks/CU (was 4). Nothing else changed.
// ---------------------------------------------------------------------------
__global__ __launch_bounds__(256, 4) void attn_kernel(
    const float* __restrict__ ac,
    const float* __restrict__ alpha,
    const float* __restrict__ Wkey_,
    const float* __restrict__ u,
    const float* __restrict__ bias,
    const float* __restrict__ q,
    const float* __restrict__ kws,
    const u16* __restrict__ XT,
    const u16* __restrict__ Wt,
    float* __restrict__ out)
{
    __shared__ __align__(16) u16 sU16[9216];  // 18 KB union: sKU fp32[4608] | sP[32][256] | sVals[16][520]
    __shared__ float sRed[MROWS * 16];        // 2 KB, [m][lg]
    __shared__ float sM[MROWS];
    __shared__ float sInvS[MROWS];

    float* sKU = (float*)sU16;

    const int tid = threadIdx.x;
    const int bid = blockIdx.x;
    const int ch = bid & 63;
    const int f  = (bid >> 6) & 7;
    const int b  = bid >> 9;
    const int bf = b * NF + f;
    const int t0 = ch * TT;

    // ---- stage K (fp32) and U ----
    {
        const float4* k4 = (const float4*)(kws + ((size_t)bf << 12));
        float4* d4 = (float4*)sKU;
        #pragma unroll
        for (int i = 0; i < 4; ++i) d4[i * 256 + tid] = k4[i * 256 + tid];
        if (tid < 128) ((float4*)(sKU + 4096))[tid] = ((const float4*)(u + f * 512))[tid];
    }
    __syncthreads();

    const int h  = tid & 7;
    const int tp = (tid >> 3) & 1;
    const int lg = tid >> 4;          // 0..15
    const int t_a = t0 + tp * 2, t_b = t_a + 1;
    const int m_a = tp * 16 + h, m_b = m_a + 8;   // m_a&15 = h, m_b&15 = h+8
    const int lbase = lg * 16;

    // ---- per-row constants (registers, 2 rows per thread) ----
    float q0a, q1a, kt0a, kt1a, c2a, c1a;
    float q0b, q1b, kt0b, kt1b, c2b, c1b;
    {
        float al = alpha[f];
        float acv = ac[f * 8 + h];
        float wk0 = Wkey_[f * 4],     wk1 = Wkey_[f * 4 + 1];
        float wk2 = Wkey_[f * 4 + 2], wk3 = Wkey_[f * 4 + 3];
        float2 qa = *(const float2*)(q + ((size_t)(bf * NT + t_a) << 4) + (h << 1));
        float2 qb = *(const float2*)(q + ((size_t)(bf * NT + t_b) << 4) + (h << 1));
        q0a = qa.x; q1a = qa.y; q0b = qb.x; q1b = qb.y;
        kt0a = sKU[t_a * 16 + h * 2]; kt1a = sKU[t_a * 16 + h * 2 + 1];
        kt0b = sKU[t_b * 16 + h * 2]; kt1b = sKU[t_b * 16 + h * 2 + 1];
        float a0 = q0a - al, a1 = q1a + 2.f * al * acv;
        c2a = a0 * wk0 + a1 * wk2; c1a = a0 * wk1 + a1 * wk3;
        a0 = q0b - al; a1 = q1b + 2.f * al * acv;
        c2b = a0 * wk0 + a1 * wk2; c1b = a0 * wk1 + a1 * wk3;
    }

    // ---- pass A: scores into registers + running max (K/U from LDS) ----
    float sA[16], sB[16];
    float mxa = -1e30f, mxb = -1e30f;
    {
        float rela = (float)(lbase - t_a);
        #pragma unroll
        for (int j = 0; j < 16; ++j) {
            int l = lbase + j;
            float2 K = *(const float2*)(sKU + l * 16 + h * 2);
            float2 U = *(const float2*)(sKU + 4096 + l * 2);
            float relb = rela - 1.f;
            float sa = (c2a * rela + c1a) * rela;
            sa = fmaf(q0a, K.x, sa); sa = fmaf(q1a, K.y, sa);
            sa = fmaf(kt0a, U.x, sa); sa = fmaf(kt1a, U.y, sa);
            float sb = (c2b * relb + c1b) * relb;
            sb = fmaf(q0b, K.x, sb); sb = fmaf(q1b, K.y, sb);
            sb = fmaf(kt0b, U.x, sb); sb = fmaf(kt1b, U.y, sb);
            sA[j] = sa; sB[j] = sb;
            mxa = fmaxf(mxa, sa); mxb = fmaxf(mxb, sb);
            rela += 1.f;
        }
    }
    sRed[m_a * 16 + lg] = mxa;
    sRed[m_b * 16 + lg] = mxb;
    __syncthreads();                         // last sKU read is above
    if (tid < MROWS) {
        const float4* r4 = (const float4*)(sRed + tid * 16);
        float4 r0 = r4[0], r1 = r4[1], r2 = r4[2], r3 = r4[3];
        float mm = fmaxf(fmaxf(fmaxf(r0.x, r0.y), fmaxf(r0.z, r0.w)),
                         fmaxf(fmaxf(r1.x, r1.y), fmaxf(r1.z, r1.w)));
        mm = fmaxf(mm, fmaxf(fmaxf(fmaxf(r2.x, r2.y), fmaxf(r2.z, r2.w)),
                             fmaxf(fmaxf(r3.x, r3.y), fmaxf(r3.z, r3.w))));
        sM[tid] = mm;
    }
    __syncthreads();

    // ---- pass B: exp from regs, sums, P writes (OVERLAYS sKU - now dead) --
    u16* sP = sU16;
    {
        const float Ma = sM[m_a], Mb = sM[m_b];
        float suma = 0.f, sumb = 0.f;
        unsigned pka[4], pkb[4];
        float epa = 0.f, epb = 0.f;
        #pragma unroll
        for (int j = 0; j < 16; ++j) {
            float ea = __expf(sA[j] - Ma), eb = __expf(sB[j] - Mb);
            suma += ea; sumb += eb;
            if ((j & 1) == 0) { epa = ea; epb = eb; }
            else { pka[(j & 7) >> 1] = pk2(epa, ea); pkb[(j & 7) >> 1] = pk2(epb, eb); }
            if ((j & 7) == 7) {
                int chunk = lg * 2 + (j >> 3);
                int pa = chunk ^ h;
                int pb = chunk ^ (h + 8);
                *(u32x4*)&sP[m_a * 256 + pa * 8] = (u32x4){pka[0], pka[1], pka[2], pka[3]};
                *(u32x4*)&sP[m_b * 256 + pb * 8] = (u32x4){pkb[0], pkb[1], pkb[2], pkb[3]};
            }
        }
        sRed[m_a * 16 + lg] = suma;
        sRed[m_b * 16 + lg] = sumb;
    }

    // ---- prefetch XT ks=0 b-frags across the reduction barrier ----
    const int wv   = tid >> 6;
    const int lane = tid & 63;
    const int quad = lane >> 4;
    const int ln   = lane & 15;
    const int mh   = wv & 1;          // m-half for phase 3
    const int nh   = wv >> 1;         // n-half for phase 3
    const u16* xb = XT + ((size_t)bf << 14);
    short8 nb0, nb1;
    {
        int l2 = quad * 8;
        nb0 = *(const short8*)(xb + (nh * 32 + ln) * 256 + l2);
        nb1 = *(const short8*)(xb + (nh * 32 + 16 + ln) * 256 + l2);
    }
    __syncthreads();
    if (tid < MROWS) {
        const float4* r4 = (const float4*)(sRed + tid * 16);
        float4 r0 = r4[0], r1 = r4[1], r2 = r4[2], r3 = r4[3];
        float ss = ((r0.x + r0.y) + (r0.z + r0.w)) + ((r1.x + r1.y) + (r1.z + r1.w))
                 + ((r2.x + r2.y) + (r2.z + r2.w)) + ((r3.x + r3.y) + (r3.z + r3.w));
        sInvS[tid] = 1.f / ss;
    }
    __syncthreads();

    // ---- phase 3: vals = P @ X via pipelined MFMA (M=32, K=256, N=64) ----
    f32x4 acc0 = {0.f, 0.f, 0.f, 0.f}, acc1 = acc0;
    #pragma unroll
    for (int ks = 0; ks < 8; ++ks) {
        short8 b0 = nb0, b1 = nb1;
        if (ks < 7) {
            int l2 = (ks + 1) * 32 + quad * 8;
            nb0 = *(const short8*)(xb + (nh * 32 + ln) * 256 + l2);
            nb1 = *(const short8*)(xb + (nh * 32 + 16 + ln) * 256 + l2);
        }
        int phys = (ks * 4 + quad) ^ ln;
        short8 a = *(const short8*)&sP[(mh * 16 + ln) * 256 + phys * 8];
        acc0 = __builtin_amdgcn_mfma_f32_16x16x32_bf16(a, b0, acc0, 0, 0, 0);
        acc1 = __builtin_amdgcn_mfma_f32_16x16x32_bf16(a, b1, acc1, 0, 0, 0);
    }
    float inv0 = sInvS[mh * 16 + quad * 4 + 0];
    float inv1 = sInvS[mh * 16 + quad * 4 + 1];
    float inv2 = sInvS[mh * 16 + quad * 4 + 2];
    float inv3 = sInvS[mh * 16 + quad * 4 + 3];
    const u16* wb = Wt + ((size_t)(f * 64 + wv * 16 + ln) << 9);
    short8 nw = *(const short8*)(wb + quad * 8);   // prefetch phase-4 ks=0
    __syncthreads();                         // all sP reads complete

    // ---- sVals (overlays the same region) ----
    u16* sVals = sU16;   // [tl][520]
    {
        float invs[4] = {inv0, inv1, inv2, inv3};
        #pragma unroll
        for (int reg = 0; reg < 4; ++reg) {
            int mg = mh * 16 + quad * 4 + reg;
            int tl = mg >> 3, hh = mg & 7;
            u16* dst = sVals + tl * 520 + hh * 64 + nh * 32 + ln;
            dst[0]  = f2bf(acc0[reg] * invs[reg]);
            dst[16] = f2bf(acc1[reg] * invs[reg]);
        }
    }
    __syncthreads();

    // ---- phase 4: out = vals @ W via pipelined MFMA (M=4(pad16), K=512) ----
    f32x4 oacc = {0.f, 0.f, 0.f, 0.f};
    #pragma unroll
    for (int ks = 0; ks < 16; ++ks) {
        short8 bw = nw;
        if (ks < 15) nw = *(const short8*)(wb + (ks + 1) * 32 + quad * 8);
        short8 a = *(const short8*)(sVals + ln * 520 + ks * 32 + quad * 8);
        oacc = __builtin_amdgcn_mfma_f32_16x16x32_bf16(a, bw, oacc, 0, 0, 0);
    }
    {
        int o = wv * 16 + ln;
        #pragma unroll
        for (int reg = 0; reg < 4; ++reg) {
            int tl = quad * 4 + reg;
            if (tl < TT) {
                int tg = t0 + tl;
                out[((size_t)(bf * NT + tg) << 6) + o] =
                    oacc[reg] + bias[((size_t)(f * NT + tg) << 6) + o];
            }
        }
    }
}

extern "C" void kernel_launch(void* const* d_in, const int* in_sizes, int n_in,
                              void* d_out, int out_size, void* d_ws, size_t ws_size,
                              hipStream_t stream) {
    const float* X     = (const float*)d_in[0];
    const float* ac    = (const float*)d_in[1];
    const float* alpha = (const float*)d_in[2];
    const float* Wq    = (const float*)d_in[3];
    const float* Wk    = (const float*)d_in[4];
    const float* Wkey_ = (const float*)d_in[5];
    const float* u     = (const float*)d_in[6];
    const float* W     = (const float*)d_in[7];
    const float* bb    = (const float*)d_in[8];
    float* out = (float*)d_out;

    float* qws = (float*)d_ws;                  // 131072 f
    float* kws = qws + 131072;                  // 131072 f
    u16* XT = (u16*)(kws + 131072);             // 524288 u16
    u16* Wt = XT + 524288;                      // 262144 u16

    hipLaunchKernelGGL(prep_kernel, dim3(2240), dim3(256), 0, stream,
                       X, Wq, Wk, W, qws, kws, XT, Wt);
    hipLaunchKernelGGL(attn_kernel, dim3(BS * NF * NCH), dim3(256), 0, stream,
                       ac, alpha, Wkey_, u, bb, qws, kws, XT, Wt, out);
}